// Round 1
// baseline (144.185 us; speedup 1.0000x reference)
//
#include <hip/hip_runtime.h>
#include <stdint.h>

#define B_    16
#define CIN_  128
#define COUT_ 128
#define H_    64
#define W_    64
#define L_    4096
#define KK_   1152
#define PW_   66                 // padded image dim (halo 1 each side)
#define PPIX_ (PW_ * PW_)        // 4356

typedef unsigned short u16;
typedef __bf16 bf16x8 __attribute__((ext_vector_type(8)));
typedef float  floatx4 __attribute__((ext_vector_type(4)));
typedef uint32_t u32x4 __attribute__((ext_vector_type(4)));

typedef const __attribute__((address_space(1))) uint32_t* gptr_t;
typedef __attribute__((address_space(3))) uint32_t*       lptr_t;

__device__ __forceinline__ void async_copy16(const void* g, void* l) {
    // stages 64 lanes x 16 B = 1024 B; LDS dest = wave-uniform base + lane*16
    __builtin_amdgcn_global_load_lds((gptr_t)g, (lptr_t)l, 16, 0, 0);
}

__device__ __forceinline__ u16 f2bf(float f) {
    uint32_t u = __builtin_bit_cast(uint32_t, f);
    uint32_t r = u + 0x7FFFu + ((u >> 16) & 1u);   // round-to-nearest-even
    return (u16)(r >> 16);
}

// ---------------------------------------------------------------------------
// P1: x [B][CIN][64][64] f32 -> xTp [B][66][66][CIN] bf16, halo zeroed.
// ---------------------------------------------------------------------------
__global__ void lmc_transpose_kernel(const float* __restrict__ x, u16* __restrict__ xTp) {
    __shared__ u16 tile[64][CIN_ + 8];
    const int b   = blockIdx.y;
    const int y   = blockIdx.x;        // 0..63
    const int tid = threadIdx.x;

    // phase A: read coalesced along l, convert, scatter into tile[x][c]
    {
        const int c  = tid >> 1;
        const int x0 = (tid & 1) * 32;
        const float* src = x + ((size_t)b * CIN_ + c) * L_ + y * 64 + x0;
        #pragma unroll
        for (int j = 0; j < 32; j += 4) {
            float4 v = *reinterpret_cast<const float4*>(src + j);
            tile[x0 + j + 0][c] = f2bf(v.x);
            tile[x0 + j + 1][c] = f2bf(v.y);
            tile[x0 + j + 2][c] = f2bf(v.z);
            tile[x0 + j + 3][c] = f2bf(v.w);
        }
    }
    __syncthreads();

    u16* dstrow = xTp + ((size_t)(b * PW_ + (y + 1)) * PW_) * CIN_;  // pixel (y+1, 0)
    // phase B: write interior pixels (y+1, x+1), coalesced in c
    {
        const int xx   = tid >> 2;
        const int cseg = (tid & 3) * 32;
        u16* dst = dstrow + (size_t)(xx + 1) * CIN_ + cseg;
        #pragma unroll
        for (int i = 0; i < 32; i += 8) {
            *reinterpret_cast<uint4*>(dst + i) =
                *reinterpret_cast<const uint4*>(&tile[xx][cseg + i]);
        }
    }
    const uint4 z = {0u, 0u, 0u, 0u};
    // x-halo: pixels (y+1, 0) and (y+1, 65)
    if (tid < 32) {
        const int pix = (tid >> 4) ? 65 : 0;
        *reinterpret_cast<uint4*>(dstrow + (size_t)pix * CIN_ + (tid & 15) * 8) = z;
    }
    // y-halo rows 0 and 65
    if (y == 0 || y == 63) {
        u16* brow = xTp + ((size_t)(b * PW_ + (y == 0 ? 0 : 65)) * PW_) * CIN_;
        for (int i = tid; i < (PW_ * CIN_) / 8; i += 256)   // 1056 uint4
            reinterpret_cast<uint4*>(brow)[i] = z;
    }
}

// ---------------------------------------------------------------------------
// P2 fused: blocks 0..127  -> mb[o][l] = bias[o] + sum_k mw[o][k]*mask[k][l]
//           blocks 128..191 -> wb2[k][o][c] = bf16(weight[o][c][k])
// ---------------------------------------------------------------------------
__global__ void lmc_prep_kernel(const float* __restrict__ mask, const float* __restrict__ mw,
                                const float* __restrict__ bias, const float* __restrict__ w,
                                float* __restrict__ mb, u16* __restrict__ wb2) {
    const int bid = blockIdx.x, tid = threadIdx.x;
    if (bid < 128) {
        const int o = bid;
        float m[9];
        #pragma unroll
        for (int k = 0; k < 9; ++k) m[k] = mw[o * 9 + k];
        const float bs = bias[o];
        for (int l = tid; l < L_; l += 256) {
            float s = bs;
            #pragma unroll
            for (int k = 0; k < 9; ++k) s += m[k] * mask[k * L_ + l];
            mb[o * L_ + l] = s;
        }
    } else {
        const int base = (bid - 128) * 2304;
        #pragma unroll
        for (int i = 0; i < 9; ++i) {
            const int e = base + i * 256 + tid;        // 0..147455 exact
            const int k = e >> 14;                     // /16384
            const int rem = e & 16383;
            const int o = rem >> 7, c = rem & 127;
            wb2[e] = f2bf(w[(size_t)o * KK_ + c * 9 + k]);
        }
    }
}

// ---------------------------------------------------------------------------
// Main GEMM: out[b][o][l] = sum_k mask[k,l] * (sum_c wb2[k][o][c]*xTp[b][pix_k(l)][c]) + mb[o][l]
// 128(o) x 128(l) tile, 4 waves of 64x64, mfma 16x16x32 bf16.
//  - XCD-chunked block swizzle: each XCD owns 2 whole batches -> xTp L2-resident.
//  - A (wb2, 288 KB total, every block reads it) fragments read DIRECT from
//    global (L1/L2-hot) -> no A staging, LDS traffic halved.
//  - B (xTp) double-buffered in LDS: stage tap k+1 while computing tap k;
//    ONE __syncthreads per tap, its vmcnt(0) drain covered by the tap's MFMAs.
// Mask applied as bitwise AND on B-fragments (mask is binary -> exact).
// ---------------------------------------------------------------------------
__global__ __launch_bounds__(256, 2)
void lmc_gemm_kernel(const u16* __restrict__ xTp, const u16* __restrict__ wb2,
                     const float* __restrict__ mask, const float* __restrict__ mb,
                     float* __restrict__ out) {
    __shared__ u16 B_lds[2 * 128 * 128];   // 2 x 32 KB, [l][c] rows 256 B, XOR-8 chunk swizzle

    // XCD-aware bijective swizzle (512 blocks, 8 XCDs, 512%8==0):
    // flat id round-robins XCDs -> XCD X gets logical [64X, 64X+64) = 2 full batches.
    const int flat    = blockIdx.y * gridDim.x + blockIdx.x;   // 0..511
    const int logical = (flat & 7) * 64 + (flat >> 3);
    const int b       = logical >> 5;
    const int l0      = (logical & 31) * 128;

    const int tid  = threadIdx.x;
    const int lane = tid & 63;
    const int wv   = tid >> 6;
    const int wm   = (wv >> 1) * 64;
    const int wn   = (wv & 1) * 64;
    const int lrow = lane & 15;
    const int quad = lane >> 4;

    // staging geometry: seg s=0..7 per wave; row = wv*32 + s*4 + (lane>>4)
    // stored chunk slot (lane&15) holds data chunk (lane&15)^(row&7)  [XOR swizzle]
    uint32_t goffB[8];  // byte offset into xTp (includes b, +1 halo shift), tap-invariant
    #pragma unroll
    for (int s = 0; s < 8; ++s) {
        const int row = wv * 32 + s * 4 + (lane >> 4);
        const int cc  = (lane & 15) ^ (row & 7);
        const int l  = l0 + row;
        const int yy = (l >> 6) + 1, xx = (l & 63) + 1;
        const int p  = (b * PW_ + yy) * PW_ + xx;
        goffB[s] = (uint32_t)(p * 256 + cc * 16);
    }

    // pre-pack mask bits: bit (k*4+j) = mask[k][l0+wn+j*16+lrow] != 0
    uint64_t bits = 0;
    #pragma unroll
    for (int j = 0; j < 4; ++j) {
        const int l = l0 + wn + j * 16 + lrow;
        #pragma unroll
        for (int k = 0; k < 9; ++k)
            if (mask[k * L_ + l] != 0.0f) bits |= (1ull << (k * 4 + j));
    }

    floatx4 acc[4][4];
    #pragma unroll
    for (int i = 0; i < 4; ++i)
        #pragma unroll
        for (int j = 0; j < 4; ++j)
            acc[i][j] = (floatx4){0.f, 0.f, 0.f, 0.f};

    const char* xTp_c = (const char*)xTp;
    char* Bb = (char*)B_lds;
    const int ldsbase = (wv * 8) * 1024;

    // prologue: stage tap 0 (dy=-1,dx=-1) into buffer 0
    {
        const int tapoff = (-PW_ - 1) * 256;
        #pragma unroll
        for (int s = 0; s < 8; ++s)
            async_copy16(xTp_c + (int)goffB[s] + tapoff, Bb + ldsbase + s * 1024);
    }
    __syncthreads();

    for (int k = 0; k < 9; ++k) {
        const int cur = (k & 1) * 32768;       // byte offset of current B buffer
        // stage NEXT tap into the other buffer (safe: that buffer was last read
        // in iter k-1, whose trailing barrier all waves have passed)
        if (k < 8) {
            const int kn = k + 1;
            const int dy = kn / 3 - 1;
            const int dx = kn - (kn / 3) * 3 - 1;
            const int tapoff = (dy * PW_ + dx) * 256;
            char* Bnxt = Bb + (32768 - cur);
            #pragma unroll
            for (int s = 0; s < 8; ++s)
                async_copy16(xTp_c + (int)goffB[s] + tapoff, Bnxt + ldsbase + s * 1024);
        }

        // A fragments direct from global: wb2[k][o][c], plain layout, L1/L2-hot
        bf16x8 af[4][4];
        const u16* wk = wb2 + k * 16384;
        #pragma unroll
        for (int i = 0; i < 4; ++i)
            #pragma unroll
            for (int ks = 0; ks < 4; ++ks)
                af[i][ks] = *reinterpret_cast<const bf16x8*>(
                    wk + (wm + i * 16 + lrow) * 128 + ks * 32 + quad * 8);

        uint32_t kp[4];
        #pragma unroll
        for (int j = 0; j < 4; ++j)
            kp[j] = 0u - (uint32_t)((bits >> (k * 4 + j)) & 1ull);

        const u16* Bc = (const u16*)(Bb + cur);
        #pragma unroll
        for (int ks = 0; ks < 4; ++ks) {
            const int sc = ((ks * 4 + quad) ^ (lrow & 7)) * 8;   // swizzled chunk
            bf16x8 bfr[4];
            #pragma unroll
            for (int j = 0; j < 4; ++j) {
                bf16x8 v = *reinterpret_cast<const bf16x8*>(&Bc[(wn + j * 16 + lrow) * 128 + sc]);
                u32x4 t = __builtin_bit_cast(u32x4, v);
                t &= kp[j];
                bfr[j] = __builtin_bit_cast(bf16x8, t);
            }
            #pragma unroll
            for (int i = 0; i < 4; ++i)
                #pragma unroll
                for (int j = 0; j < 4; ++j)
                    acc[i][j] = __builtin_amdgcn_mfma_f32_16x16x32_bf16(af[i][ks], bfr[j], acc[i][j], 0, 0, 0);
        }
        // one barrier per tap: drains the (covered) next-tap staging AND
        // signals all waves done reading the current buffer
        __syncthreads();
    }

    // epilogue: C/D layout col = lane&15 (l), row = quad*4 + r (o)
    #pragma unroll
    for (int i = 0; i < 4; ++i) {
        #pragma unroll
        for (int j = 0; j < 4; ++j) {
            const int l = l0 + wn + j * 16 + lrow;
            #pragma unroll
            for (int r = 0; r < 4; ++r) {
                const int o = wm + i * 16 + quad * 4 + r;
                out[((size_t)b * COUT_ + o) * L_ + l] = acc[i][j][r] + mb[o * L_ + l];
            }
        }
    }
}

// ---------------------------------------------------------------------------
extern "C" void kernel_launch(void* const* d_in, const int* in_sizes, int n_in,
                              void* d_out, int out_size, void* d_ws, size_t ws_size,
                              hipStream_t stream) {
    const float* x      = (const float*)d_in[0];
    const float* mask   = (const float*)d_in[1];
    const float* weight = (const float*)d_in[2];
    const float* mw     = (const float*)d_in[3];
    const float* bias   = (const float*)d_in[4];
    float* out = (float*)d_out;

    char* ws = (char*)d_ws;
    u16*   xTp = (u16*)ws;                                  // 16*4356*128*2 = 17,842,176 B
    u16*   wb2 = (u16*)(ws + 17842176);                     // 294,912 B  [9][128][128] bf16
    float* mb  = (float*)(ws + 17842176 + 294912);          // 2,097,152 B [128][4096] f32

    lmc_transpose_kernel<<<dim3(64, B_), 256, 0, stream>>>(x, xTp);
    lmc_prep_kernel<<<192, 256, 0, stream>>>(mask, mw, bias, weight, mb, wb2);
    lmc_gemm_kernel<<<dim3(L_ / 128, B_), 256, 0, stream>>>(xTp, wb2, mask, mb, out);
}

// Round 2
// 143.319 us; speedup vs baseline: 1.0060x; 1.0060x over previous
//
#include <hip/hip_runtime.h>
#include <stdint.h>

#define B_    16
#define CIN_  128
#define COUT_ 128
#define H_    64
#define W_    64
#define L_    4096
#define KK_   1152
#define PW_   66                 // padded image dim (halo 1 each side)
#define PPIX_ (PW_ * PW_)        // 4356

typedef unsigned short u16;
typedef __bf16 bf16x8 __attribute__((ext_vector_type(8)));
typedef float  floatx4 __attribute__((ext_vector_type(4)));
typedef uint32_t u32x4 __attribute__((ext_vector_type(4)));

typedef const __attribute__((address_space(1))) uint32_t* gptr_t;
typedef __attribute__((address_space(3))) uint32_t*       lptr_t;

__device__ __forceinline__ void async_copy16(const void* g, void* l) {
    // stages 64 lanes x 16 B = 1024 B; LDS dest = wave-uniform base + lane*16
    __builtin_amdgcn_global_load_lds((gptr_t)g, (lptr_t)l, 16, 0, 0);
}

__device__ __forceinline__ u16 f2bf(float f) {
    uint32_t u = __builtin_bit_cast(uint32_t, f);
    uint32_t r = u + 0x7FFFu + ((u >> 16) & 1u);   // round-to-nearest-even
    return (u16)(r >> 16);
}

// ---------------------------------------------------------------------------
// P1: x [B][CIN][64][64] f32 -> xTp [B][66][66][CIN] bf16, halo zeroed.
// ---------------------------------------------------------------------------
__global__ void lmc_transpose_kernel(const float* __restrict__ x, u16* __restrict__ xTp) {
    __shared__ u16 tile[64][CIN_ + 8];
    const int b   = blockIdx.y;
    const int y   = blockIdx.x;        // 0..63
    const int tid = threadIdx.x;

    // phase A: read coalesced along l, convert, scatter into tile[x][c]
    {
        const int c  = tid >> 1;
        const int x0 = (tid & 1) * 32;
        const float* src = x + ((size_t)b * CIN_ + c) * L_ + y * 64 + x0;
        #pragma unroll
        for (int j = 0; j < 32; j += 4) {
            float4 v = *reinterpret_cast<const float4*>(src + j);
            tile[x0 + j + 0][c] = f2bf(v.x);
            tile[x0 + j + 1][c] = f2bf(v.y);
            tile[x0 + j + 2][c] = f2bf(v.z);
            tile[x0 + j + 3][c] = f2bf(v.w);
        }
    }
    __syncthreads();

    u16* dstrow = xTp + ((size_t)(b * PW_ + (y + 1)) * PW_) * CIN_;  // pixel (y+1, 0)
    // phase B: write interior pixels (y+1, x+1), coalesced in c
    {
        const int xx   = tid >> 2;
        const int cseg = (tid & 3) * 32;
        u16* dst = dstrow + (size_t)(xx + 1) * CIN_ + cseg;
        #pragma unroll
        for (int i = 0; i < 32; i += 8) {
            *reinterpret_cast<uint4*>(dst + i) =
                *reinterpret_cast<const uint4*>(&tile[xx][cseg + i]);
        }
    }
    const uint4 z = {0u, 0u, 0u, 0u};
    // x-halo: pixels (y+1, 0) and (y+1, 65)
    if (tid < 32) {
        const int pix = (tid >> 4) ? 65 : 0;
        *reinterpret_cast<uint4*>(dstrow + (size_t)pix * CIN_ + (tid & 15) * 8) = z;
    }
    // y-halo rows 0 and 65
    if (y == 0 || y == 63) {
        u16* brow = xTp + ((size_t)(b * PW_ + (y == 0 ? 0 : 65)) * PW_) * CIN_;
        for (int i = tid; i < (PW_ * CIN_) / 8; i += 256)   // 1056 uint4
            reinterpret_cast<uint4*>(brow)[i] = z;
    }
}

// ---------------------------------------------------------------------------
// P2 fused: blocks 0..127  -> mb[o][l] = bias[o] + sum_k mw[o][k]*mask[k][l]
//           blocks 128..191 -> wb2[k][o][c] = bf16(weight[o][c][k])
// ---------------------------------------------------------------------------
__global__ void lmc_prep_kernel(const float* __restrict__ mask, const float* __restrict__ mw,
                                const float* __restrict__ bias, const float* __restrict__ w,
                                float* __restrict__ mb, u16* __restrict__ wb2) {
    const int bid = blockIdx.x, tid = threadIdx.x;
    if (bid < 128) {
        const int o = bid;
        float m[9];
        #pragma unroll
        for (int k = 0; k < 9; ++k) m[k] = mw[o * 9 + k];
        const float bs = bias[o];
        for (int l = tid; l < L_; l += 256) {
            float s = bs;
            #pragma unroll
            for (int k = 0; k < 9; ++k) s += m[k] * mask[k * L_ + l];
            mb[o * L_ + l] = s;
        }
    } else {
        const int base = (bid - 128) * 2304;
        #pragma unroll
        for (int i = 0; i < 9; ++i) {
            const int e = base + i * 256 + tid;        // 0..147455 exact
            const int k = e >> 14;                     // /16384
            const int rem = e & 16383;
            const int o = rem >> 7, c = rem & 127;
            wb2[e] = f2bf(w[(size_t)o * KK_ + c * 9 + k]);
        }
    }
}

// ---------------------------------------------------------------------------
// Main GEMM, window-resident version.
// Block = 128(o) x 256(l) tile = 4 image rows. The 9 taps of those 256 pixels
// all live in a 6-row x 66-col window of xTp: 396 px * 256 B = 101,376 B LDS,
// staged ONCE (per-pixel XOR-8 chunk swizzle via pre-swizzled global source).
// Main loop: 9 taps of pure ds_read+MFMA, ZERO barriers, zero re-staging.
// A (wb2, 32 KB/tap, L1/L2-hot) rolls through registers: af[*][ks] for tap
// k+1 is loaded right after its last use in tap k (in-place, no extra VGPR,
// latency covered by ~600 cycles of MFMA).
// Grid = exactly 256 blocks (16 b x 16 ltiles) of 8 waves -> 1 block/CU,
// zero tail; XCD-chunked swizzle -> each XCD reads only 2 batches of xTp.
// Mask applied as bitwise AND on B-fragments (mask is binary -> exact).
// ---------------------------------------------------------------------------
__global__ __launch_bounds__(512, 2)
void lmc_gemm_kernel(const u16* __restrict__ xTp, const u16* __restrict__ wb2,
                     const float* __restrict__ mask, const float* __restrict__ mb,
                     float* __restrict__ out) {
    __shared__ u16 W_lds[396 * 128];   // 101,376 B

    // XCD-chunked bijective swizzle (256 blocks, 8 XCDs): XCD X gets logical
    // [32X, 32X+32) = 2 whole batches -> per-XCD L2 working set ~2.2 MB.
    const int flat    = blockIdx.x;                  // 0..255
    const int logical = (flat & 7) * 32 + (flat >> 3);
    const int b       = logical >> 4;
    const int lt      = logical & 15;
    const int Y       = lt * 4;                      // first image row of tile
    const int l0      = lt * 256;

    const int tid  = threadIdx.x;
    const int lane = tid & 63;
    const int wv   = tid >> 6;                       // 0..7
    const int wm   = (wv >> 2) * 64;                 // o offset  {0,64}
    const int wn   = (wv & 3) * 64;                  // l offset  {0,64,128,192}
    const int lrow = lane & 15;
    const int quad = lane >> 4;

    // ---- prologue: stage 6x66 pixel window (padded rows Y..Y+5, all cols) ----
    // window pixel p (0..395) chunk slot s holds data chunk s^(p&7).
    // global_load_lds dest is linear (base + lane*16); swizzle goes on source.
    {
        const char* xw = (const char*)xTp + ((size_t)(b * PW_ + Y) * PW_) * 256;
        for (int t = wv; t < 99; t += 8) {           // 99 instrs, 4 px each
            const int p    = t * 4 + quad;           // this lane's pixel
            const int srcc = lrow ^ (p & 7);         // source chunk for slot lrow
            async_copy16(xw + (size_t)p * 256 + srcc * 16,
                         (char*)W_lds + t * 1024);
        }
    }

    // ---- A fragments for tap 0 (rolling register buffer) ----
    int arow[4];
    #pragma unroll
    for (int i = 0; i < 4; ++i)
        arow[i] = (wm + i * 16 + lrow) * 128 + quad * 8;

    bf16x8 af[4][4];
    #pragma unroll
    for (int i = 0; i < 4; ++i)
        #pragma unroll
        for (int ks = 0; ks < 4; ++ks)
            af[i][ks] = *reinterpret_cast<const bf16x8*>(wb2 + arow[i] + ks * 32);

    // ---- per-lane window pixel bases + mask bit-pack ----
    int pix0[4];
    uint64_t bits = 0;
    #pragma unroll
    for (int j = 0; j < 4; ++j) {
        const int ll = wn + j * 16 + lrow;           // block-local l 0..255
        pix0[j] = ((ll >> 6) + 1) * 66 + (ll & 63) + 1;
        const int lg = l0 + ll;
        #pragma unroll
        for (int k = 0; k < 9; ++k)
            if (mask[k * L_ + lg] != 0.0f) bits |= (1ull << (k * 4 + j));
    }

    floatx4 acc[4][4];
    #pragma unroll
    for (int i = 0; i < 4; ++i)
        #pragma unroll
        for (int j = 0; j < 4; ++j)
            acc[i][j] = (floatx4){0.f, 0.f, 0.f, 0.f};

    __syncthreads();   // drains window staging (vmcnt(0)); the ONLY barrier

    // ---- main loop: 9 taps, no barriers, no staging ----
    for (int k = 0; k < 9; ++k) {
        const int dy = k / 3 - 1;
        const int dx = k - (k / 3) * 3 - 1;
        const int sh = dy * 66 + dx;                 // window pixel shift
        const int kn = (k < 8) ? k + 1 : 8;          // clamp: last iter reloads (dead)
        const u16* wkn = wb2 + kn * 16384;

        uint32_t kp[4];
        #pragma unroll
        for (int j = 0; j < 4; ++j)
            kp[j] = 0u - (uint32_t)((bits >> (k * 4 + j)) & 1ull);

        #pragma unroll
        for (int ks = 0; ks < 4; ++ks) {
            bf16x8 bfr[4];
            #pragma unroll
            for (int j = 0; j < 4; ++j) {
                const int pix  = pix0[j] + sh;
                const int slot = (ks * 4 + quad) ^ (pix & 7);
                bf16x8 v = *reinterpret_cast<const bf16x8*>(&W_lds[pix * 128 + slot * 8]);
                u32x4 t = __builtin_bit_cast(u32x4, v);
                t &= kp[j];
                bfr[j] = __builtin_bit_cast(bf16x8, t);
            }
            #pragma unroll
            for (int i = 0; i < 4; ++i)
                #pragma unroll
                for (int j = 0; j < 4; ++j)
                    acc[i][j] = __builtin_amdgcn_mfma_f32_16x16x32_bf16(af[i][ks], bfr[j], acc[i][j], 0, 0, 0);
            // roll A: af[*][ks] dead now -> load next tap's slice in place
            #pragma unroll
            for (int i = 0; i < 4; ++i)
                af[i][ks] = *reinterpret_cast<const bf16x8*>(wkn + arow[i] + ks * 32);
        }
    }

    // ---- epilogue: C/D layout col = lane&15 (l), row = quad*4 + r (o) ----
    #pragma unroll
    for (int i = 0; i < 4; ++i) {
        #pragma unroll
        for (int j = 0; j < 4; ++j) {
            const int l = l0 + wn + j * 16 + lrow;
            #pragma unroll
            for (int r = 0; r < 4; ++r) {
                const int o = wm + i * 16 + quad * 4 + r;
                out[((size_t)b * COUT_ + o) * L_ + l] = acc[i][j][r] + mb[o * L_ + l];
            }
        }
    }
}

// ---------------------------------------------------------------------------
extern "C" void kernel_launch(void* const* d_in, const int* in_sizes, int n_in,
                              void* d_out, int out_size, void* d_ws, size_t ws_size,
                              hipStream_t stream) {
    const float* x      = (const float*)d_in[0];
    const float* mask   = (const float*)d_in[1];
    const float* weight = (const float*)d_in[2];
    const float* mw     = (const float*)d_in[3];
    const float* bias   = (const float*)d_in[4];
    float* out = (float*)d_out;

    char* ws = (char*)d_ws;
    u16*   xTp = (u16*)ws;                                  // 16*4356*128*2 = 17,842,176 B
    u16*   wb2 = (u16*)(ws + 17842176);                     // 294,912 B  [9][128][128] bf16
    float* mb  = (float*)(ws + 17842176 + 294912);          // 2,097,152 B [128][4096] f32

    lmc_transpose_kernel<<<dim3(64, B_), 256, 0, stream>>>(x, xTp);
    lmc_prep_kernel<<<192, 256, 0, stream>>>(mask, mw, bias, weight, mb, wb2);
    lmc_gemm_kernel<<<dim3(256), 512, 0, stream>>>(xTp, wb2, mask, mb, out);
}

// Round 3
// 142.019 us; speedup vs baseline: 1.0153x; 1.0092x over previous
//
#include <hip/hip_runtime.h>
#include <stdint.h>

#define B_    16
#define CIN_  128
#define COUT_ 128
#define H_    64
#define W_    64
#define L_    4096
#define KK_   1152
#define PW_   66                 // padded image dim (halo 1 each side)
#define PPIX_ (PW_ * PW_)        // 4356

typedef unsigned short u16;
typedef __bf16 bf16x8 __attribute__((ext_vector_type(8)));
typedef float  floatx4 __attribute__((ext_vector_type(4)));
typedef uint32_t u32x4 __attribute__((ext_vector_type(4)));

typedef const __attribute__((address_space(1))) uint32_t* gptr_t;
typedef __attribute__((address_space(3))) uint32_t*       lptr_t;

__device__ __forceinline__ void async_copy16(const void* g, void* l) {
    // stages 64 lanes x 16 B = 1024 B; LDS dest = wave-uniform base + lane*16
    __builtin_amdgcn_global_load_lds((gptr_t)g, (lptr_t)l, 16, 0, 0);
}

__device__ __forceinline__ u16 f2bf(float f) {
    uint32_t u = __builtin_bit_cast(uint32_t, f);
    uint32_t r = u + 0x7FFFu + ((u >> 16) & 1u);   // round-to-nearest-even
    return (u16)(r >> 16);
}

// ---------------------------------------------------------------------------
// Fused prep: blocks 0..1023   -> transpose x -> xTp [B][66][66][CIN] bf16
//             blocks 1024..1151 -> mb[o][l] = bias[o] + sum_k mw[o][k]*mask[k][l]
//             blocks 1152..1215 -> wb2[k][o][c] = bf16(weight[o][c][k])
// (P1+P2 merged: one launch gap removed; P2 work rides along.)
// ---------------------------------------------------------------------------
__global__ void lmc_prep_kernel(const float* __restrict__ x,
                                const float* __restrict__ mask, const float* __restrict__ mw,
                                const float* __restrict__ bias, const float* __restrict__ w,
                                u16* __restrict__ xTp, float* __restrict__ mb,
                                u16* __restrict__ wb2) {
    const int bid = blockIdx.x, tid = threadIdx.x;
    if (bid < 1024) {
        // ---- transpose: x [B][CIN][64][64] f32 -> xTp bf16, halo zeroed ----
        __shared__ u16 tile[64][CIN_ + 8];
        const int b = bid >> 6;
        const int y = bid & 63;

        {
            const int c  = tid >> 1;
            const int x0 = (tid & 1) * 32;
            const float* src = x + ((size_t)b * CIN_ + c) * L_ + y * 64 + x0;
            #pragma unroll
            for (int j = 0; j < 32; j += 4) {
                float4 v = *reinterpret_cast<const float4*>(src + j);
                tile[x0 + j + 0][c] = f2bf(v.x);
                tile[x0 + j + 1][c] = f2bf(v.y);
                tile[x0 + j + 2][c] = f2bf(v.z);
                tile[x0 + j + 3][c] = f2bf(v.w);
            }
        }
        __syncthreads();

        u16* dstrow = xTp + ((size_t)(b * PW_ + (y + 1)) * PW_) * CIN_;  // pixel (y+1, 0)
        {
            const int xx   = tid >> 2;
            const int cseg = (tid & 3) * 32;
            u16* dst = dstrow + (size_t)(xx + 1) * CIN_ + cseg;
            #pragma unroll
            for (int i = 0; i < 32; i += 8) {
                *reinterpret_cast<uint4*>(dst + i) =
                    *reinterpret_cast<const uint4*>(&tile[xx][cseg + i]);
            }
        }
        const uint4 z = {0u, 0u, 0u, 0u};
        if (tid < 32) {
            const int pix = (tid >> 4) ? 65 : 0;
            *reinterpret_cast<uint4*>(dstrow + (size_t)pix * CIN_ + (tid & 15) * 8) = z;
        }
        if (y == 0 || y == 63) {
            u16* brow = xTp + ((size_t)(b * PW_ + (y == 0 ? 0 : 65)) * PW_) * CIN_;
            for (int i = tid; i < (PW_ * CIN_) / 8; i += 256)   // 1056 uint4
                reinterpret_cast<uint4*>(brow)[i] = z;
        }
    } else if (bid < 1152) {
        // ---- mb ----
        const int o = bid - 1024;
        float m[9];
        #pragma unroll
        for (int k = 0; k < 9; ++k) m[k] = mw[o * 9 + k];
        const float bs = bias[o];
        for (int l = tid; l < L_; l += 256) {
            float s = bs;
            #pragma unroll
            for (int k = 0; k < 9; ++k) s += m[k] * mask[k * L_ + l];
            mb[o * L_ + l] = s;
        }
    } else {
        // ---- wb2 repack ----
        const int base = (bid - 1152) * 2304;
        #pragma unroll
        for (int i = 0; i < 9; ++i) {
            const int e = base + i * 256 + tid;        // 0..147455 exact
            const int k = e >> 14;                     // /16384
            const int rem = e & 16383;
            const int o = rem >> 7, c = rem & 127;
            wb2[e] = f2bf(w[(size_t)o * KK_ + c * 9 + k]);
        }
    }
}

// ---------------------------------------------------------------------------
// Main GEMM, window-resident, 2 blocks/CU, register-double-buffered B.
// Block = 128(o) x 128(l) tile = 2 image rows; window 4x66 = 264 px = 67.6 KB
// LDS -> TWO independent blocks per CU (staging of one overlaps compute of
// the other; no shared barrier). 4 waves of 64x64.
// B fragments double-buffered in registers (bA/bB): each step issues the NEXT
// step's 4 ds_read_b128, then runs 16 MFMAs on the current ones -> LDS latency
// hidden. A (wb2, L1/L2-hot) rolls through registers as before.
// Mask applied as bitwise AND on B-fragments (mask is binary -> exact).
// ---------------------------------------------------------------------------
#define SH_(k) (((k) / 3 - 1) * 66 + ((k) % 3 - 1))

// one pipeline step: compute (k,ks) from `cur`, prefetch (kn,ksn) into `nxt`,
// then roll af[*][ks] to tap k+1. All array indices are unroll-constants.
#define GSTEP(cur, nxt, k, ks, DO_LOAD, kn, ksn)                              \
    do {                                                                      \
        if (DO_LOAD) {                                                        \
            const int shn = SH_(kn);                                          \
            _Pragma("unroll")                                                 \
            for (int j = 0; j < 4; ++j) {                                     \
                const int pixn  = pix0[j] + shn;                              \
                const int slotn = ((ksn) * 4 + quad) ^ (pixn & 7);            \
                nxt[j] = *reinterpret_cast<const bf16x8*>(                    \
                            &W_lds[pixn * 128 + slotn * 8]);                  \
            }                                                                 \
        }                                                                     \
        bf16x8 bm[4];                                                         \
        _Pragma("unroll")                                                     \
        for (int j = 0; j < 4; ++j) {                                         \
            u32x4 t = __builtin_bit_cast(u32x4, cur[j]);                      \
            t &= kp[j];                                                       \
            bm[j] = __builtin_bit_cast(bf16x8, t);                            \
        }                                                                     \
        _Pragma("unroll")                                                     \
        for (int i = 0; i < 4; ++i)                                           \
            _Pragma("unroll")                                                 \
            for (int j = 0; j < 4; ++j)                                       \
                acc[i][j] = __builtin_amdgcn_mfma_f32_16x16x32_bf16(          \
                    af[i][ks], bm[j], acc[i][j], 0, 0, 0);                    \
        _Pragma("unroll")                                                     \
        for (int i = 0; i < 4; ++i)                                           \
            af[i][ks] = *reinterpret_cast<const bf16x8*>(                     \
                wkn + arow[i] + (ks) * 32);                                   \
    } while (0)

__global__ __launch_bounds__(256, 2)
void lmc_gemm_kernel(const u16* __restrict__ xTp, const u16* __restrict__ wb2,
                     const float* __restrict__ mask, const float* __restrict__ mb,
                     float* __restrict__ out) {
    __shared__ u16 W_lds[264 * 128];   // 67,584 B -> 2 blocks/CU

    // XCD-chunked bijective swizzle (512 blocks, 8 XCDs): XCD X gets logical
    // [64X, 64X+64) = 2 whole batches -> per-XCD xTp working set ~2.2 MB.
    const int flat    = blockIdx.x;                  // 0..511
    const int logical = (flat & 7) * 64 + (flat >> 3);
    const int b       = logical >> 5;
    const int lt      = logical & 31;                // 0..31
    const int Y       = lt * 2;                      // first image row of tile
    const int l0      = lt * 128;

    const int tid  = threadIdx.x;
    const int lane = tid & 63;
    const int wv   = tid >> 6;                       // 0..3
    const int wm   = (wv >> 1) * 64;                 // o offset  {0,64}
    const int wn   = (wv & 1) * 64;                  // l offset  {0,64}
    const int lrow = lane & 15;
    const int quad = lane >> 4;

    // ---- prologue: stage 4x66 pixel window (padded rows Y..Y+3) ----
    // window pixel p: slot s holds data chunk s^(p&7); linear LDS dest,
    // swizzle applied on the global source chunk.
    {
        const char* xw = (const char*)xTp + ((size_t)(b * PW_ + Y) * PW_) * 256;
        for (int t = wv; t < 66; t += 4) {           // 66 instrs, 4 px each
            const int p    = t * 4 + quad;
            const int srcc = lrow ^ (p & 7);
            async_copy16(xw + (size_t)p * 256 + srcc * 16,
                         (char*)W_lds + t * 1024);
        }
    }

    // ---- A fragments for tap 0 (rolling register buffer) ----
    int arow[4];
    #pragma unroll
    for (int i = 0; i < 4; ++i)
        arow[i] = (wm + i * 16 + lrow) * 128 + quad * 8;

    bf16x8 af[4][4];
    #pragma unroll
    for (int i = 0; i < 4; ++i)
        #pragma unroll
        for (int ks = 0; ks < 4; ++ks)
            af[i][ks] = *reinterpret_cast<const bf16x8*>(wb2 + arow[i] + ks * 32);

    // ---- per-lane window pixel bases + mask bit-pack ----
    int pix0[4];
    uint64_t bits = 0;
    #pragma unroll
    for (int j = 0; j < 4; ++j) {
        const int ll = wn + j * 16 + lrow;           // block-local l 0..127
        pix0[j] = ((ll >> 6) + 1) * 66 + (ll & 63) + 1;
        const int lg = l0 + ll;
        #pragma unroll
        for (int k = 0; k < 9; ++k)
            if (mask[k * L_ + lg] != 0.0f) bits |= (1ull << (k * 4 + j));
    }

    floatx4 acc[4][4];
    #pragma unroll
    for (int i = 0; i < 4; ++i)
        #pragma unroll
        for (int j = 0; j < 4; ++j)
            acc[i][j] = (floatx4){0.f, 0.f, 0.f, 0.f};

    __syncthreads();   // drains window staging; the ONLY barrier

    // ---- main loop: 36 steps, software-pipelined B, no barriers ----
    bf16x8 bA[4], bB[4];
    {   // preload step (0,0) into bA
        const int sh0 = SH_(0);
        #pragma unroll
        for (int j = 0; j < 4; ++j) {
            const int pix  = pix0[j] + sh0;
            const int slot = quad ^ (pix & 7);
            bA[j] = *reinterpret_cast<const bf16x8*>(&W_lds[pix * 128 + slot * 8]);
        }
    }

    #pragma unroll
    for (int k = 0; k < 9; ++k) {
        const u16* wkn = wb2 + ((k < 8) ? (k + 1) : 8) * 16384;
        uint32_t kp[4];
        #pragma unroll
        for (int j = 0; j < 4; ++j)
            kp[j] = 0u - (uint32_t)((bits >> (k * 4 + j)) & 1ull);

        GSTEP(bA, bB, k, 0, true,      k,     1);
        GSTEP(bB, bA, k, 1, true,      k,     2);
        GSTEP(bA, bB, k, 2, true,      k,     3);
        GSTEP(bB, bA, k, 3, (k < 8),   k + 1, 0);
    }

    // ---- epilogue: C/D layout col = lane&15 (l), row = quad*4 + r (o) ----
    #pragma unroll
    for (int i = 0; i < 4; ++i) {
        #pragma unroll
        for (int j = 0; j < 4; ++j) {
            const int l = l0 + wn + j * 16 + lrow;
            #pragma unroll
            for (int r = 0; r < 4; ++r) {
                const int o = wm + i * 16 + quad * 4 + r;
                out[((size_t)b * COUT_ + o) * L_ + l] = acc[i][j][r] + mb[o * L_ + l];
            }
        }
    }
}

// ---------------------------------------------------------------------------
extern "C" void kernel_launch(void* const* d_in, const int* in_sizes, int n_in,
                              void* d_out, int out_size, void* d_ws, size_t ws_size,
                              hipStream_t stream) {
    const float* x      = (const float*)d_in[0];
    const float* mask   = (const float*)d_in[1];
    const float* weight = (const float*)d_in[2];
    const float* mw     = (const float*)d_in[3];
    const float* bias   = (const float*)d_in[4];
    float* out = (float*)d_out;

    char* ws = (char*)d_ws;
    u16*   xTp = (u16*)ws;                                  // 16*4356*128*2 = 17,842,176 B
    u16*   wb2 = (u16*)(ws + 17842176);                     // 294,912 B  [9][128][128] bf16
    float* mb  = (float*)(ws + 17842176 + 294912);          // 2,097,152 B [128][4096] f32

    lmc_prep_kernel<<<1216, 256, 0, stream>>>(x, mask, mw, bias, weight, xTp, mb, wb2);
    lmc_gemm_kernel<<<512, 256, 0, stream>>>(xTp, wb2, mask, mb, out);
}